// Round 18
// baseline (37.735 us; speedup 1.0000x reference)
//
#include <hip/hip_runtime.h>

// RNNFFT: depth-10 radix-2 butterfly network over last dim (1024).
// v = x; for l = 9..0: y = B_l(w_l * v); v = (l==1) ? y : x + y
// Pairs at level l: (e, e^h), h = 512>>l. Twiddle: bw[OFF[l] + (e & (n_l-1))].
// Mix (lw^T): role-j: y = lw[j][j]*t_self + lw[1-j][j]*t_partner.
//
// Two-layout butterfly (r11/r15 = 31us best):
//   Layout A (e=lane*16+r): levels 9..6 in-lane; 5,4 via DPP quad_perm.
//   Per-wave LDS transpose (XOR-swizzled). bw staged in LDS.
//   Layout B (e=r*64+lane): levels 3..0 in-lane; coalesced B stores.
// R15 post-mortem: early global loads neutral -> global latency not the stall.
// Pipe tally/vector: DS 420 CU-cyc (11.2us) > VALU 8.9 > TA 5.3, HBM floor 15.
// This round: PHASE-MERGED PAIR. Wave processes vectors 2w,2w+1 as
// A(a) A(b) | transpose(a) transpose(b) | B(a) B(b), so loadw_A (8 b128) and
// loadw_B (30 b32) are loaded ONCE for both vectors: DS/vector 66 -> 41.
// Level-granular a/b interleave doubles in-wave ILP. Single 4KB transpose
// buffer (per-wave DS is in-order: read(a) before write(b) is hazard-free).
// xrB loads issued into dead xrA regs during transpose DS waits.
// Peak live ~110 regs -> waves_per_eu(2,4) soft cap (no r3-style forced spill).
// Per-vector arithmetic identical to r11 (absmax 7.45e-9).

constexpr int VECLEN = 1024;

__device__ __forceinline__ int swz(int f) {      // XOR bits[4:2] with bits[7:5]
  return f ^ (((f >> 5) & 7) << 2);              // preserves 16B groups
}

template<int L, bool RESL>
__device__ __forceinline__ void level_inlane(float (&v)[16], const float (&xr)[16],
                                             const float* __restrict__ bw,
                                             const float* __restrict__ lw) {
  constexpr int n = VECLEN >> L;          // 16, 8, 4, 2
  constexpr int h = n >> 1;               // 8, 4, 2, 1
  constexpr int off = 2048 - (2048 >> L); // OFFSETS[L]
  float w[n];                              // lane-uniform -> SGPR loads (CSE'd a/b)
#pragma unroll
  for (int i = 0; i < n; ++i) w[i] = bw[off + i];
  const float l00 = lw[L*4+0], l01 = lw[L*4+1], l10 = lw[L*4+2], l11 = lw[L*4+3];
#pragma unroll
  for (int r = 0; r < 16; ++r) {
    if ((r & h) == 0) {
      const int q = r ^ h;
      const float t0 = w[r & (n-1)] * v[r];
      const float t1 = w[q & (n-1)] * v[q];
      const float y0 = l00*t0 + l10*t1;   // role 0 (exact r11 ordering)
      const float y1 = l01*t0 + l11*t1;   // role 1
      v[r] = RESL ? xr[r] + y0 : y0;
      v[q] = RESL ? xr[q] + y1 : y1;
    }
  }
}

template<int L, bool RESL>
__device__ __forceinline__ void level_dpp(float (&v)[16], const float (&xr)[16],
                                          const float (&w)[16],
                                          const float* __restrict__ lw, int lane) {
  static_assert(L == 4 || L == 5, "DPP levels only");
  constexpr int ctl = (L == 5) ? 0xB1 : 0x4E;
  const int role = (lane >> (5 - L)) & 1;
  const float l00 = lw[L*4+0], l01 = lw[L*4+1], l10 = lw[L*4+2], l11 = lw[L*4+3];
  const float cs = role ? l11 : l00;
  const float cp = role ? l01 : l10;
#pragma unroll
  for (int r = 0; r < 16; ++r) {
    const float t = w[r] * v[r];
    const float tp = __int_as_float(
        __builtin_amdgcn_update_dpp(0, __float_as_int(t), ctl, 0xF, 0xF, true));
    const float y = cs*t + cp*tp;
    v[r] = RESL ? xr[r] + y : y;
  }
}

template<int L>
__device__ __forceinline__ void loadw_A(float (&w)[16], const float* lds_bw, int lane) {
  constexpr int n = VECLEN >> L;
  constexpr int off = 2048 - (2048 >> L);
  const int f0 = off + ((lane * 16) & (n - 1));
#pragma unroll
  for (int k = 0; k < 4; ++k) {
    const float4 f = *reinterpret_cast<const float4*>(lds_bw + swz(f0 + 4*k));
    w[4*k+0]=f.x; w[4*k+1]=f.y; w[4*k+2]=f.z; w[4*k+3]=f.w;
  }
}

template<int L>
__device__ __forceinline__ void loadw_B(float* w, const float* lds_bw, int lane) {
  constexpr int off = 2048 - (2048 >> L);
  constexpr int nr = (VECLEN >> L) >> 6;   // 16, 8, 4, 2
#pragma unroll
  for (int j = 0; j < nr; ++j)
    w[j] = lds_bw[swz(off + j*64 + lane)];
}

template<int L, bool RESL>
__device__ __forceinline__ void level_B(float (&v)[16], const float (&xr)[16],
                                        const float* w, const float* __restrict__ lw) {
  constexpr int nr = (VECLEN >> L) >> 6;   // 16, 8, 4, 2
  constexpr int hb = nr >> 1;              // 8, 4, 2, 1
  const float l00 = lw[L*4+0], l01 = lw[L*4+1], l10 = lw[L*4+2], l11 = lw[L*4+3];
#pragma unroll
  for (int r = 0; r < 16; ++r) {
    if ((r & hb) == 0) {
      const int q = r ^ hb;
      const float t0 = w[r & (nr-1)] * v[r];
      const float t1 = w[q & (nr-1)] * v[q];
      const float y0 = l00*t0 + l10*t1;
      const float y1 = l01*t0 + l11*t1;
      v[r] = RESL ? xr[r] + y0 : y0;
      v[q] = RESL ? xr[q] + y1 : y1;
    }
  }
}

__device__ __forceinline__ void loadX_A(float (&xr)[16], const float* __restrict__ x,
                                        size_t base, int lane) {
#pragma unroll
  for (int k = 0; k < 4; ++k) {
    const float4 f = *reinterpret_cast<const float4*>(x + base + lane*16 + 4*k);
    xr[4*k+0]=f.x; xr[4*k+1]=f.y; xr[4*k+2]=f.z; xr[4*k+3]=f.w;
  }
}

__device__ __forceinline__ void loadX_B(float (&xr)[16], const float* __restrict__ x,
                                        size_t base, int lane) {
#pragma unroll
  for (int r = 0; r < 16; ++r) xr[r] = x[base + r*64 + lane];
}

__global__ __launch_bounds__(256)
__attribute__((amdgpu_waves_per_eu(2, 4)))
void rnnfft_kernel(const float* __restrict__ x,
                   const float* __restrict__ bw,
                   const float* __restrict__ lw,
                   float* __restrict__ out, int nvec) {
  __shared__ float lds_bw[2048];           // swizzled bw[0..2016)  (8 KB)
  __shared__ float tbuf[4][1024];          // per-wave transpose buffer (16 KB)
  const int t = threadIdx.x;
  const int w4 = t >> 6;
  const int lane = t & 63;
  const int wid = blockIdx.x * 4 + w4;     // wave id; vectors 2*wid, 2*wid+1
  const size_t baseA = (size_t)(2 * wid) * VECLEN;
  const size_t baseB = baseA + VECLEN;
  float* buf = tbuf[w4];

  // Both vectors' A-layout residuals up front (8 independent dwordx4).
  float vA[16], vB[16], xr0[16], xr1[16];
  loadX_A(xr0, x, baseA, lane);
  loadX_A(xr1, x, baseB, lane);

  // Stage bw[0..2016) into LDS (swizzled), once per block.
  if (t < 252) {
    const float4 a = *reinterpret_cast<const float4*>(bw + 8*t);
    const float4 b = *reinterpret_cast<const float4*>(bw + 8*t + 4);
    *reinterpret_cast<float4*>(lds_bw + swz(8*t)) = a;
    *reinterpret_cast<float4*>(lds_bw + swz(8*t+4)) = b;
  }
  __syncthreads();

#pragma unroll
  for (int r = 0; r < 16; ++r) { vA[r] = xr0[r]; vB[r] = xr1[r]; }

  // ---- Phase A on both vectors, level-interleaved (shared twiddles) ----
  {
    float wA[16], wB[16];
    loadw_A<5>(wA, lds_bw, lane);          // once per wave, serves a AND b
    loadw_A<4>(wB, lds_bw, lane);
    level_inlane<9, true>(vA, xr0, bw, lw);  level_inlane<9, true>(vB, xr1, bw, lw);
    level_inlane<8, true>(vA, xr0, bw, lw);  level_inlane<8, true>(vB, xr1, bw, lw);
    level_inlane<7, true>(vA, xr0, bw, lw);  level_inlane<7, true>(vB, xr1, bw, lw);
    level_inlane<6, true>(vA, xr0, bw, lw);  level_inlane<6, true>(vB, xr1, bw, lw);
    level_dpp<5, true>(vA, xr0, wA, lw, lane); level_dpp<5, true>(vB, xr1, wA, lw, lane);
    level_dpp<4, true>(vA, xr0, wB, lw, lane); level_dpp<4, true>(vB, xr1, wB, lw, lane);
  }

  // ---- Transpose a then b through ONE per-wave buffer (in-order DS) ----
  // xrA regs are dead; refill them with B-layout residuals during the waits.
#pragma unroll
  for (int k = 0; k < 4; ++k) {
    float4 f;
    f.x = vA[4*k+0]; f.y = vA[4*k+1]; f.z = vA[4*k+2]; f.w = vA[4*k+3];
    *reinterpret_cast<float4*>(buf + swz(lane*16 + 4*k)) = f;
  }
  loadX_B(xr0, x, baseA, lane);            // rides under the DS round trip
#pragma unroll
  for (int r = 0; r < 16; ++r) vA[r] = buf[swz(r*64 + lane)];
#pragma unroll
  for (int k = 0; k < 4; ++k) {
    float4 f;
    f.x = vB[4*k+0]; f.y = vB[4*k+1]; f.z = vB[4*k+2]; f.w = vB[4*k+3];
    *reinterpret_cast<float4*>(buf + swz(lane*16 + 4*k)) = f;
  }
  loadX_B(xr1, x, baseB, lane);
#pragma unroll
  for (int r = 0; r < 16; ++r) vB[r] = buf[swz(r*64 + lane)];

  // ---- Phase B on both vectors, level-interleaved (shared twiddles) ----
  {
    float w3[2], w2[4], w1[8], w0[16];
    loadw_B<3>(w3, lds_bw, lane);          // once per wave, serves a AND b
    loadw_B<2>(w2, lds_bw, lane);
    loadw_B<1>(w1, lds_bw, lane);
    loadw_B<0>(w0, lds_bw, lane);
    level_B<3, true >(vA, xr0, w3, lw);  level_B<3, true >(vB, xr1, w3, lw);
    level_B<2, true >(vA, xr0, w2, lw);  level_B<2, true >(vB, xr1, w2, lw);
    level_B<1, false>(vA, xr0, w1, lw);  level_B<1, false>(vB, xr1, w1, lw);
    level_B<0, true >(vA, xr0, w0, lw);  level_B<0, true >(vB, xr1, w0, lw);
  }

  // ---- Stores, both vectors, coalesced in B layout ----
#pragma unroll
  for (int r = 0; r < 16; ++r) out[baseA + r*64 + lane] = vA[r];
#pragma unroll
  for (int r = 0; r < 16; ++r) out[baseB + r*64 + lane] = vB[r];
}

extern "C" void kernel_launch(void* const* d_in, const int* in_sizes, int n_in,
                              void* d_out, int out_size, void* d_ws, size_t ws_size,
                              hipStream_t stream) {
  const float* x  = (const float*)d_in[0];
  const float* bw = (const float*)d_in[1];
  const float* lw = (const float*)d_in[2];
  float* out = (float*)d_out;
  const int nvec = in_sizes[0] / VECLEN;        // 16384 vectors
  const int nwave = nvec / 2;                   // 8192 waves (2 vectors each)
  const int wpb = 4;                            // waves per block (256 threads)
  const int blocks = (nwave + wpb - 1) / wpb;   // 2048, exact
  rnnfft_kernel<<<blocks, 256, 0, stream>>>(x, bw, lw, out, nvec);
}

// Round 19
// 32.355 us; speedup vs baseline: 1.1663x; 1.1663x over previous
//
#include <hip/hip_runtime.h>

// RNNFFT: depth-10 radix-2 butterfly network over last dim (1024).
// v = x; for l = 9..0: y = B_l(w_l * v); v = (l==1) ? y : x + y
// Pairs at level l: (e, e^h), h = 512>>l. Twiddle: bw[OFF[l] + (e & (n_l-1))].
// Mix (lw^T): role-j: y = lw[j][j]*t_self + lw[1-j][j]*t_partner.
//
// R18 post-mortem: merged-pair (~110 live regs) -> allocator squeezed to 64 and
// RE-LOADED residuals from global (FETCH 33->56MB), 37.7us. Lesson: live set
// must fit ~64 VGPRs. 16-elem/lane designs pinned at 31us (latency-bound,
// ~700-cyc serial chain, ~4 waves/SIMD).
// This round: TWO WAVES PER VECTOR (8 elems/lane) - halve the chain, double
// resident waves, live set ~55 regs:
//   Layout A (e = gl*8+r, gl=wv*64+lane): L9..7 in-lane; L6 lane^1 DPP 0xB1;
//     L5 lane^2 DPP 0x4E; L4 lane^4 ds_swizzle 0x101F; L3 lane^8 0x201F.
//   LDS transpose (one __syncthreads, cross-wave) to Layout B (e = rb*128+gl):
//     L2/L1/L0 = rb^1/^2/^4 in-lane; x-reload & stores 64-consecutive/wave.
// bw[0..2016) staged in LDS (covers L0..L5); L6 twiddles (bw[2016..2032), one
// cacheline) from global; L9..7 lane-uniform scalar. Per-element FP ops
// bit-identical to r11 (sum commutation only) -> absmax 7.45e-9.

constexpr int VECLEN = 1024;

__device__ __forceinline__ int swz(int f) {      // XOR bits[4:2] with bits[7:5]
  return f ^ (((f >> 5) & 7) << 2);              // preserves 16B groups
}

// A-layout in-lane levels L9..L7 (r bits 0..2), lane-uniform twiddles.
template<int L, bool RESL>
__device__ __forceinline__ void level_inA(float (&v)[8], const float (&xr)[8],
                                          const float* __restrict__ bw,
                                          const float* __restrict__ lw) {
  constexpr int n = VECLEN >> L;          // 2, 4, 8
  constexpr int h = n >> 1;               // 1, 2, 4
  constexpr int off = 2048 - (2048 >> L); // OFFSETS[L]
  float w[n];
#pragma unroll
  for (int i = 0; i < n; ++i) w[i] = bw[off + i];
  const float l00 = lw[L*4+0], l01 = lw[L*4+1], l10 = lw[L*4+2], l11 = lw[L*4+3];
#pragma unroll
  for (int r = 0; r < 8; ++r) {
    if ((r & h) == 0) {
      const int q = r ^ h;
      const float t0 = w[r & (n-1)] * v[r];
      const float t1 = w[q & (n-1)] * v[q];
      const float y0 = l00*t0 + l10*t1;   // role 0 (exact r11 ordering)
      const float y1 = l01*t0 + l11*t1;   // role 1
      v[r] = RESL ? xr[r] + y0 : y0;
      v[q] = RESL ? xr[q] + y1 : y1;
    }
  }
}

// A-layout cross levels L6..L3: partner = lane ^ (1,2,4,8); role = gl bit (6-L).
template<int L, bool RESL>
__device__ __forceinline__ void level_x(float (&v)[8], const float (&xr)[8],
                                        const float (&w)[8],
                                        const float* __restrict__ lw, int lane) {
  static_assert(L >= 3 && L <= 6, "cross levels");
  const int role = (lane >> (6 - L)) & 1;
  const float l00 = lw[L*4+0], l01 = lw[L*4+1], l10 = lw[L*4+2], l11 = lw[L*4+3];
  const float cs = role ? l11 : l00;      // coeff on own t
  const float cp = role ? l01 : l10;      // coeff on partner t
#pragma unroll
  for (int r = 0; r < 8; ++r) {
    const float t = w[r] * v[r];
    const int ti = __float_as_int(t);
    int pi;
    if constexpr (L == 6) pi = __builtin_amdgcn_update_dpp(0, ti, 0xB1, 0xF, 0xF, true); // ^1
    else if constexpr (L == 5) pi = __builtin_amdgcn_update_dpp(0, ti, 0x4E, 0xF, 0xF, true); // ^2
    else if constexpr (L == 4) pi = __builtin_amdgcn_ds_swizzle(ti, 0x101F);  // ^4
    else pi = __builtin_amdgcn_ds_swizzle(ti, 0x201F);                        // ^8
    const float tp = __int_as_float(pi);
    const float y = cs*t + cp*tp;
    v[r] = RESL ? xr[r] + y : y;
  }
}

// L6 twiddles from global (bw[2016..2032), single cacheline, L1-resident).
__device__ __forceinline__ void loadw6(float (&w)[8], const float* __restrict__ bw,
                                       int lane) {
  const int b = 2016 + (lane & 1) * 8;
  const float4 f0 = *reinterpret_cast<const float4*>(bw + b);
  const float4 f1 = *reinterpret_cast<const float4*>(bw + b + 4);
  w[0]=f0.x; w[1]=f0.y; w[2]=f0.z; w[3]=f0.w;
  w[4]=f1.x; w[5]=f1.y; w[6]=f1.z; w[7]=f1.w;
}

// L5/L4/L3 twiddles from LDS: idx = (lane & (n/8-1))*8 + r.
template<int L>
__device__ __forceinline__ void loadwX(float (&w)[8], const float* lds_bw, int lane) {
  constexpr int n = VECLEN >> L;           // 32, 64, 128
  constexpr int off = 2048 - (2048 >> L);
  const int b = off + ((lane * 8) & (n - 1));
  const float4 f0 = *reinterpret_cast<const float4*>(lds_bw + swz(b));
  const float4 f1 = *reinterpret_cast<const float4*>(lds_bw + swz(b + 4));
  w[0]=f0.x; w[1]=f0.y; w[2]=f0.z; w[3]=f0.w;
  w[4]=f1.x; w[5]=f1.y; w[6]=f1.z; w[7]=f1.w;
}

// B-layout twiddles: w[j] = bw[off + j*128 + gl].
template<int L>
__device__ __forceinline__ void loadwB(float* w, const float* lds_bw, int gl) {
  constexpr int off = 2048 - (2048 >> L);
  constexpr int nw = (VECLEN >> L) >> 7;   // L2:2, L1:4, L0:8
#pragma unroll
  for (int j = 0; j < nw; ++j)
    w[j] = lds_bw[swz(off + j*128 + gl)];
}

// B-layout in-lane levels (rb bits): pair rb^hb; twiddle w[rb & (nw-1)].
template<int L, bool RESL>
__device__ __forceinline__ void level_B(float (&v)[8], const float (&xr)[8],
                                        const float* w, const float* __restrict__ lw) {
  constexpr int nw = (VECLEN >> L) >> 7;   // 2, 4, 8
  constexpr int hb = nw >> 1;              // 1, 2, 4
  const float l00 = lw[L*4+0], l01 = lw[L*4+1], l10 = lw[L*4+2], l11 = lw[L*4+3];
#pragma unroll
  for (int rb = 0; rb < 8; ++rb) {
    if ((rb & hb) == 0) {
      const int q = rb ^ hb;
      const float t0 = w[rb & (nw-1)] * v[rb];
      const float t1 = w[q & (nw-1)] * v[q];
      const float y0 = l00*t0 + l10*t1;
      const float y1 = l01*t0 + l11*t1;
      v[rb] = RESL ? xr[rb] + y0 : y0;
      v[q]  = RESL ? xr[q]  + y1 : y1;
    }
  }
}

__global__ __launch_bounds__(256)
void rnnfft_kernel(const float* __restrict__ x,
                   const float* __restrict__ bw,
                   const float* __restrict__ lw,
                   float* __restrict__ out, int nvec) {
  __shared__ float lds_bw[2048];           // swizzled bw[0..2016)  (8 KB)
  __shared__ float tbuf[2][1024];          // per-vector transpose buffer (8 KB)
  const int t = threadIdx.x;
  const int lane = t & 63;
  const int wv = (t >> 6) & 1;             // which half of the vector
  const int p  = t >> 7;                   // which vector of the block
  const int gl = wv * 64 + lane;           // global lane within vector (0..127)
  const int vid = blockIdx.x * 2 + p;
  const size_t base = (size_t)vid * VECLEN;

  // A-layout residual: e = gl*8 + r (two dwordx4).
  float v[8], xr[8];
  {
    const float4 f0 = *reinterpret_cast<const float4*>(x + base + gl*8);
    const float4 f1 = *reinterpret_cast<const float4*>(x + base + gl*8 + 4);
    xr[0]=f0.x; xr[1]=f0.y; xr[2]=f0.z; xr[3]=f0.w;
    xr[4]=f1.x; xr[5]=f1.y; xr[6]=f1.z; xr[7]=f1.w;
  }

  // Stage bw[0..2016) into LDS (swizzled), once per block.
  if (t < 252) {
    const float4 a = *reinterpret_cast<const float4*>(bw + 8*t);
    const float4 b = *reinterpret_cast<const float4*>(bw + 8*t + 4);
    *reinterpret_cast<float4*>(lds_bw + swz(8*t)) = a;
    *reinterpret_cast<float4*>(lds_bw + swz(8*t+4)) = b;
  }
  __syncthreads();

#pragma unroll
  for (int r = 0; r < 8; ++r) v[r] = xr[r];

  // Per-lane twiddles for the cross levels (issued up front).
  float w6[8], w5[8], w4[8], w3[8];
  loadw6(w6, bw, lane);
  loadwX<5>(w5, lds_bw, lane);
  loadwX<4>(w4, lds_bw, lane);
  loadwX<3>(w3, lds_bw, lane);

  // Layout A: levels 9..3 (all intra-wave).
  level_inA<9, true>(v, xr, bw, lw);
  level_inA<8, true>(v, xr, bw, lw);
  level_inA<7, true>(v, xr, bw, lw);
  level_x<6, true>(v, xr, w6, lw, lane);
  level_x<5, true>(v, xr, w5, lw, lane);
  level_x<4, true>(v, xr, w4, lw, lane);
  level_x<3, true>(v, xr, w3, lw, lane);

  // Transpose A -> B through the vector's shared buffer (cross-wave).
  float* buf = tbuf[p];
  {
    float4 f0, f1;
    f0.x=v[0]; f0.y=v[1]; f0.z=v[2]; f0.w=v[3];
    f1.x=v[4]; f1.y=v[5]; f1.z=v[6]; f1.w=v[7];
    *reinterpret_cast<float4*>(buf + swz(gl*8))     = f0;
    *reinterpret_cast<float4*>(buf + swz(gl*8 + 4)) = f1;
  }
  // B-layout residual + twiddles ride under the barrier.
  float xrB[8];
#pragma unroll
  for (int rb = 0; rb < 8; ++rb) xrB[rb] = x[base + rb*128 + gl];
  float w2[2], w1[4], w0[8];
  loadwB<2>(w2, lds_bw, gl);
  loadwB<1>(w1, lds_bw, gl);
  loadwB<0>(w0, lds_bw, gl);
  __syncthreads();

#pragma unroll
  for (int rb = 0; rb < 8; ++rb) v[rb] = buf[swz(rb*128 + gl)];

  // Layout B: levels 2..0 in-lane.
  level_B<2, true >(v, xrB, w2, lw);
  level_B<1, false>(v, xrB, w1, lw);   // RES[1] = False
  level_B<0, true >(v, xrB, w0, lw);

  // Coalesced stores: 64 consecutive floats per wave per rb.
#pragma unroll
  for (int rb = 0; rb < 8; ++rb) out[base + rb*128 + gl] = v[rb];
}

extern "C" void kernel_launch(void* const* d_in, const int* in_sizes, int n_in,
                              void* d_out, int out_size, void* d_ws, size_t ws_size,
                              hipStream_t stream) {
  const float* x  = (const float*)d_in[0];
  const float* bw = (const float*)d_in[1];
  const float* lw = (const float*)d_in[2];
  float* out = (float*)d_out;
  const int nvec = in_sizes[0] / VECLEN;        // 16384 vectors
  const int blocks = nvec / 2;                  // 2 vectors per 256-thread block
  rnnfft_kernel<<<blocks, 256, 0, stream>>>(x, bw, lw, out, nvec);
}

// Round 20
// 31.402 us; speedup vs baseline: 1.2016x; 1.0303x over previous
//
#include <hip/hip_runtime.h>

// RNNFFT: depth-10 radix-2 butterfly network over last dim (1024).
// v = x; for l = 9..0: y = B_l(w_l * v); v = (l==1) ? y : x + y
// Pairs at level l: (e, e^h), h = 512>>l. Twiddle: bw[OFF[l] + (e & (n_l-1))].
// Mix (lw^T): role-j: y = lw[j][j]*t_self + lw[1-j][j]*t_partner.
//
// Two-layout butterfly (r11 = 31.0us best):
//   Layout A (e=lane*16+r): levels 9..6 in-lane; 5,4 via DPP quad_perm.
//   Per-wave LDS transpose (XOR-swizzled). bw staged in LDS.
//   Layout B (e=r*64+lane): levels 3..0 in-lane; coalesced B stores.
// Ledger: occupancy up (r4,r19) neutral/worse; VALU down (r14) neutral; latency
// hiding (r15) neutral; DS down via reg pressure (r18) regressed (allocator
// re-reads globals when live>~64 regs). VALUBusy ~35%, HBM ~50% - balanced mix.
// This round: ELIMINATE THE SECOND GLOBAL READ OF x. r11 re-read x in B-layout
// for the L2..L0 residuals - 16 late L2 round trips/wave (L1 thrashed: ~80KB
// active vectors vs 32KB L1). Now xr is written to a second per-wave LDS
// buffer (4 x b128, swizzled) RIGHT AFTER the x load (~2000 cyc before use,
// DS pipe idle there), and xrB is read back (16 x b32) alongside the vB reads.
// One global read of x + one write of out = minimal traffic. LDS 40KB/block
// (4 blocks/CU, same effective occupancy as r11). xrB reuses xr registers.
// LDS passthrough is bit-exact -> absmax 7.450581e-9 unchanged.

constexpr int VECLEN = 1024;

__device__ __forceinline__ int swz(int f) {      // XOR bits[4:2] with bits[7:5]
  return f ^ (((f >> 5) & 7) << 2);              // preserves 16B groups
}

template<int L, bool RESL>
__device__ __forceinline__ void level_inlane(float (&v)[16], const float (&xr)[16],
                                             const float* __restrict__ bw,
                                             const float* __restrict__ lw) {
  constexpr int n = VECLEN >> L;          // 16, 8, 4, 2
  constexpr int h = n >> 1;               // 8, 4, 2, 1
  constexpr int off = 2048 - (2048 >> L); // OFFSETS[L]
  float w[n];                              // lane-uniform -> scalar loads
#pragma unroll
  for (int i = 0; i < n; ++i) w[i] = bw[off + i];
  const float l00 = lw[L*4+0], l01 = lw[L*4+1], l10 = lw[L*4+2], l11 = lw[L*4+3];
#pragma unroll
  for (int r = 0; r < 16; ++r) {
    if ((r & h) == 0) {
      const int q = r ^ h;
      const float t0 = w[r & (n-1)] * v[r];
      const float t1 = w[q & (n-1)] * v[q];
      const float y0 = l00*t0 + l10*t1;   // role 0 (exact r11 ordering)
      const float y1 = l01*t0 + l11*t1;   // role 1
      v[r] = RESL ? xr[r] + y0 : y0;
      v[q] = RESL ? xr[q] + y1 : y1;
    }
  }
}

template<int L, bool RESL>
__device__ __forceinline__ void level_dpp(float (&v)[16], const float (&xr)[16],
                                          const float (&w)[16],
                                          const float* __restrict__ lw, int lane) {
  static_assert(L == 4 || L == 5, "DPP levels only");
  constexpr int ctl = (L == 5) ? 0xB1 : 0x4E;
  const int role = (lane >> (5 - L)) & 1;
  const float l00 = lw[L*4+0], l01 = lw[L*4+1], l10 = lw[L*4+2], l11 = lw[L*4+3];
  const float cs = role ? l11 : l00;      // coeff on own t
  const float cp = role ? l01 : l10;      // coeff on partner t
#pragma unroll
  for (int r = 0; r < 16; ++r) {
    const float t = w[r] * v[r];
    const float tp = __int_as_float(
        __builtin_amdgcn_update_dpp(0, __float_as_int(t), ctl, 0xF, 0xF, true));
    const float y = cs*t + cp*tp;
    v[r] = RESL ? xr[r] + y : y;
  }
}

template<int L>
__device__ __forceinline__ void loadw_A(float (&w)[16], const float* lds_bw, int lane) {
  constexpr int n = VECLEN >> L;
  constexpr int off = 2048 - (2048 >> L);
  const int f0 = off + ((lane * 16) & (n - 1));
#pragma unroll
  for (int k = 0; k < 4; ++k) {
    const float4 f = *reinterpret_cast<const float4*>(lds_bw + swz(f0 + 4*k));
    w[4*k+0]=f.x; w[4*k+1]=f.y; w[4*k+2]=f.z; w[4*k+3]=f.w;
  }
}

template<int L>
__device__ __forceinline__ void loadw_B(float* w, const float* lds_bw, int lane) {
  constexpr int off = 2048 - (2048 >> L);
  constexpr int nr = (VECLEN >> L) >> 6;   // 16, 8, 4, 2
#pragma unroll
  for (int j = 0; j < nr; ++j)
    w[j] = lds_bw[swz(off + j*64 + lane)];
}

template<int L, bool RESL>
__device__ __forceinline__ void level_B(float (&v)[16], const float (&xr)[16],
                                        const float* w, const float* __restrict__ lw) {
  constexpr int nr = (VECLEN >> L) >> 6;   // 16, 8, 4, 2
  constexpr int hb = nr >> 1;              // 8, 4, 2, 1
  const float l00 = lw[L*4+0], l01 = lw[L*4+1], l10 = lw[L*4+2], l11 = lw[L*4+3];
#pragma unroll
  for (int r = 0; r < 16; ++r) {
    if ((r & hb) == 0) {
      const int q = r ^ hb;
      const float t0 = w[r & (nr-1)] * v[r];
      const float t1 = w[q & (nr-1)] * v[q];
      const float y0 = l00*t0 + l10*t1;
      const float y1 = l01*t0 + l11*t1;
      v[r] = RESL ? xr[r] + y0 : y0;
      v[q] = RESL ? xr[q] + y1 : y1;
    }
  }
}

__global__ __launch_bounds__(256)
void rnnfft_kernel(const float* __restrict__ x,
                   const float* __restrict__ bw,
                   const float* __restrict__ lw,
                   float* __restrict__ out, int nvec) {
  __shared__ float lds_bw[2048];           // swizzled bw[0..2016)  (8 KB)
  __shared__ float tbuf_v[4][1024];        // per-wave v transpose (16 KB)
  __shared__ float tbuf_x[4][1024];        // per-wave xr transpose (16 KB)
  const int t = threadIdx.x;
  const int w4 = t >> 6;
  const int lane = t & 63;
  const int wid = blockIdx.x * 4 + w4;     // wave id = vector id (grid exact)
  const size_t base = (size_t)wid * VECLEN;
  float* bufv = tbuf_v[w4];
  float* bufx = tbuf_x[w4];

  // x in layout A (the ONLY global read of x).
  float v[16], xr[16];
#pragma unroll
  for (int k = 0; k < 4; ++k) {
    const float4 f = *reinterpret_cast<const float4*>(x + base + lane*16 + 4*k);
    xr[4*k+0]=f.x; xr[4*k+1]=f.y; xr[4*k+2]=f.z; xr[4*k+3]=f.w;
  }

  // Immediately stash xr into the per-wave LDS transpose buffer — it will be
  // read back in B layout ~2000 cycles later (DS pipe idle during phase A).
#pragma unroll
  for (int k = 0; k < 4; ++k) {
    float4 f;
    f.x = xr[4*k+0]; f.y = xr[4*k+1]; f.z = xr[4*k+2]; f.w = xr[4*k+3];
    *reinterpret_cast<float4*>(bufx + swz(lane*16 + 4*k)) = f;
  }

  // Stage bw[0..2016) into LDS (swizzled), once per block.
  if (t < 252) {
    const float4 a = *reinterpret_cast<const float4*>(bw + 8*t);
    const float4 b = *reinterpret_cast<const float4*>(bw + 8*t + 4);
    *reinterpret_cast<float4*>(lds_bw + swz(8*t)) = a;
    *reinterpret_cast<float4*>(lds_bw + swz(8*t+4)) = b;
  }
  __syncthreads();

#pragma unroll
  for (int r = 0; r < 16; ++r) v[r] = xr[r];

  // Prefetch DPP-level twiddles from LDS (land during in-lane levels).
  float wA[16], wB[16];
  loadw_A<5>(wA, lds_bw, lane);
  loadw_A<4>(wB, lds_bw, lane);

  // Layout A: levels 9..6 in-lane, 5 and 4 via DPP.
  level_inlane<9, true>(v, xr, bw, lw);
  level_inlane<8, true>(v, xr, bw, lw);
  level_inlane<7, true>(v, xr, bw, lw);
  level_inlane<6, true>(v, xr, bw, lw);
  level_dpp<5, true>(v, xr, wA, lw, lane);
  level_dpp<4, true>(v, xr, wB, lw, lane);

  // Transpose v: A -> B (per-wave buffer, in-order DS, no barrier needed).
#pragma unroll
  for (int k = 0; k < 4; ++k) {
    float4 f;
    f.x = v[4*k+0]; f.y = v[4*k+1]; f.z = v[4*k+2]; f.w = v[4*k+3];
    *reinterpret_cast<float4*>(bufv + swz(lane*16 + 4*k)) = f;
  }

  // B-twiddles for the first two B-levels ride the same DS queue.
  float w3[2], w2[4], w1[8], w0[16];
  loadw_B<3>(w3, lds_bw, lane);
  loadw_B<2>(w2, lds_bw, lane);

  // Read back BOTH v and xr in B layout from LDS (xr regs reused; no global).
#pragma unroll
  for (int r = 0; r < 16; ++r) v[r]  = bufv[swz(r*64 + lane)];
#pragma unroll
  for (int r = 0; r < 16; ++r) xr[r] = bufx[swz(r*64 + lane)];

  // Layout B: levels 3..0 all in-lane (pure VALU).
  level_B<3, true >(v, xr, w3, lw);
  loadw_B<1>(w1, lds_bw, lane);
  level_B<2, true >(v, xr, w2, lw);
  loadw_B<0>(w0, lds_bw, lane);
  level_B<1, false>(v, xr, w1, lw);   // RES[1] = False
  level_B<0, true >(v, xr, w0, lw);

  // Store directly in B-layout: 16 coalesced 256B dword stores.
#pragma unroll
  for (int r = 0; r < 16; ++r) out[base + r*64 + lane] = v[r];
}

extern "C" void kernel_launch(void* const* d_in, const int* in_sizes, int n_in,
                              void* d_out, int out_size, void* d_ws, size_t ws_size,
                              hipStream_t stream) {
  const float* x  = (const float*)d_in[0];
  const float* bw = (const float*)d_in[1];
  const float* lw = (const float*)d_in[2];
  float* out = (float*)d_out;
  const int nvec = in_sizes[0] / VECLEN;        // 16384 vectors
  const int wpb = 4;                            // waves per block (256 threads)
  const int blocks = (nvec + wpb - 1) / wpb;    // 4096, exact
  rnnfft_kernel<<<blocks, 256, 0, stream>>>(x, bw, lw, out, nvec);
}

// Round 22
// 30.526 us; speedup vs baseline: 1.2361x; 1.0287x over previous
//
#include <hip/hip_runtime.h>

// RNNFFT: depth-10 radix-2 butterfly network over last dim (1024).
// v = x; for l = 9..0: y = B_l(w_l * v); v = (l==1) ? y : x + y
// Pairs at level l: (e, e^h), h = 512>>l. Twiddle: bw[OFF[l] + (e & (n_l-1))].
// Mix (lw^T): role-j: y = lw[j][j]*t_self + lw[1-j][j]*t_partner.
//
// Two-layout butterfly (r11/r20 = 31.0/31.4us):
//   Layout A (e=lane*16+r): levels 9..6 in-lane; 5,4 via DPP quad_perm.
//   Per-wave LDS transpose (XOR-swizzled). bw staged in LDS. xr passed to
//   B-layout through a second LDS buffer (single global read of x, r20).
//   Layout B (e=r*64+lane): levels 3..0 in-lane; coalesced B stores.
// Ledger of nulls: occupancy (r4,r19), VALU count (r14), load latency (r15),
// DS count (r16/r18, register-blocked), VMEM count (r20), twiddle source (r13),
// packing (r12,r14). Pinned 31.0-31.4us, VALU ~35%, fabric ~4.2/6.5 TB/s.
// This round: NONTEMPORAL STORES for out. Counters show FETCH=33MB for a 64MB
// input: out's write-allocation evicts half of x from the 256MB L3 every
// replay, forcing compulsory HBM re-fetch + doubling HBM pressure in the
// store burst. out is never re-read -> stream it past L2/L3 (gfx950 'nt').
// Predicted: FETCH 33 -> <15MB, dur 31.4 -> 27-29us; absmax bit-identical.

constexpr int VECLEN = 1024;

__device__ __forceinline__ int swz(int f) {      // XOR bits[4:2] with bits[7:5]
  return f ^ (((f >> 5) & 7) << 2);              // preserves 16B groups
}

template<int L, bool RESL>
__device__ __forceinline__ void level_inlane(float (&v)[16], const float (&xr)[16],
                                             const float* __restrict__ bw,
                                             const float* __restrict__ lw) {
  constexpr int n = VECLEN >> L;          // 16, 8, 4, 2
  constexpr int h = n >> 1;               // 8, 4, 2, 1
  constexpr int off = 2048 - (2048 >> L); // OFFSETS[L]
  float w[n];                              // lane-uniform -> scalar loads
#pragma unroll
  for (int i = 0; i < n; ++i) w[i] = bw[off + i];
  const float l00 = lw[L*4+0], l01 = lw[L*4+1], l10 = lw[L*4+2], l11 = lw[L*4+3];
#pragma unroll
  for (int r = 0; r < 16; ++r) {
    if ((r & h) == 0) {
      const int q = r ^ h;
      const float t0 = w[r & (n-1)] * v[r];
      const float t1 = w[q & (n-1)] * v[q];
      const float y0 = l00*t0 + l10*t1;   // role 0 (exact r11 ordering)
      const float y1 = l01*t0 + l11*t1;   // role 1
      v[r] = RESL ? xr[r] + y0 : y0;
      v[q] = RESL ? xr[q] + y1 : y1;
    }
  }
}

template<int L, bool RESL>
__device__ __forceinline__ void level_dpp(float (&v)[16], const float (&xr)[16],
                                          const float (&w)[16],
                                          const float* __restrict__ lw, int lane) {
  static_assert(L == 4 || L == 5, "DPP levels only");
  constexpr int ctl = (L == 5) ? 0xB1 : 0x4E;
  const int role = (lane >> (5 - L)) & 1;
  const float l00 = lw[L*4+0], l01 = lw[L*4+1], l10 = lw[L*4+2], l11 = lw[L*4+3];
  const float cs = role ? l11 : l00;      // coeff on own t
  const float cp = role ? l01 : l10;      // coeff on partner t
#pragma unroll
  for (int r = 0; r < 16; ++r) {
    const float t = w[r] * v[r];
    const float tp = __int_as_float(
        __builtin_amdgcn_update_dpp(0, __float_as_int(t), ctl, 0xF, 0xF, true));
    const float y = cs*t + cp*tp;
    v[r] = RESL ? xr[r] + y : y;
  }
}

template<int L>
__device__ __forceinline__ void loadw_A(float (&w)[16], const float* lds_bw, int lane) {
  constexpr int n = VECLEN >> L;
  constexpr int off = 2048 - (2048 >> L);
  const int f0 = off + ((lane * 16) & (n - 1));
#pragma unroll
  for (int k = 0; k < 4; ++k) {
    const float4 f = *reinterpret_cast<const float4*>(lds_bw + swz(f0 + 4*k));
    w[4*k+0]=f.x; w[4*k+1]=f.y; w[4*k+2]=f.z; w[4*k+3]=f.w;
  }
}

template<int L>
__device__ __forceinline__ void loadw_B(float* w, const float* lds_bw, int lane) {
  constexpr int off = 2048 - (2048 >> L);
  constexpr int nr = (VECLEN >> L) >> 6;   // 16, 8, 4, 2
#pragma unroll
  for (int j = 0; j < nr; ++j)
    w[j] = lds_bw[swz(off + j*64 + lane)];
}

template<int L, bool RESL>
__device__ __forceinline__ void level_B(float (&v)[16], const float (&xr)[16],
                                        const float* w, const float* __restrict__ lw) {
  constexpr int nr = (VECLEN >> L) >> 6;   // 16, 8, 4, 2
  constexpr int hb = nr >> 1;              // 8, 4, 2, 1
  const float l00 = lw[L*4+0], l01 = lw[L*4+1], l10 = lw[L*4+2], l11 = lw[L*4+3];
#pragma unroll
  for (int r = 0; r < 16; ++r) {
    if ((r & hb) == 0) {
      const int q = r ^ hb;
      const float t0 = w[r & (nr-1)] * v[r];
      const float t1 = w[q & (nr-1)] * v[q];
      const float y0 = l00*t0 + l10*t1;
      const float y1 = l01*t0 + l11*t1;
      v[r] = RESL ? xr[r] + y0 : y0;
      v[q] = RESL ? xr[q] + y1 : y1;
    }
  }
}

__global__ __launch_bounds__(256)
void rnnfft_kernel(const float* __restrict__ x,
                   const float* __restrict__ bw,
                   const float* __restrict__ lw,
                   float* __restrict__ out, int nvec) {
  __shared__ float lds_bw[2048];           // swizzled bw[0..2016)  (8 KB)
  __shared__ float tbuf_v[4][1024];        // per-wave v transpose (16 KB)
  __shared__ float tbuf_x[4][1024];        // per-wave xr transpose (16 KB)
  const int t = threadIdx.x;
  const int w4 = t >> 6;
  const int lane = t & 63;
  const int wid = blockIdx.x * 4 + w4;     // wave id = vector id (grid exact)
  const size_t base = (size_t)wid * VECLEN;
  float* bufv = tbuf_v[w4];
  float* bufx = tbuf_x[w4];

  // x in layout A (the ONLY global read of x).
  float v[16], xr[16];
#pragma unroll
  for (int k = 0; k < 4; ++k) {
    const float4 f = *reinterpret_cast<const float4*>(x + base + lane*16 + 4*k);
    xr[4*k+0]=f.x; xr[4*k+1]=f.y; xr[4*k+2]=f.z; xr[4*k+3]=f.w;
  }

  // Immediately stash xr into the per-wave LDS transpose buffer — read back
  // in B layout ~2000 cycles later (DS pipe idle during phase A).
#pragma unroll
  for (int k = 0; k < 4; ++k) {
    float4 f;
    f.x = xr[4*k+0]; f.y = xr[4*k+1]; f.z = xr[4*k+2]; f.w = xr[4*k+3];
    *reinterpret_cast<float4*>(bufx + swz(lane*16 + 4*k)) = f;
  }

  // Stage bw[0..2016) into LDS (swizzled), once per block.
  if (t < 252) {
    const float4 a = *reinterpret_cast<const float4*>(bw + 8*t);
    const float4 b = *reinterpret_cast<const float4*>(bw + 8*t + 4);
    *reinterpret_cast<float4*>(lds_bw + swz(8*t)) = a;
    *reinterpret_cast<float4*>(lds_bw + swz(8*t+4)) = b;
  }
  __syncthreads();

#pragma unroll
  for (int r = 0; r < 16; ++r) v[r] = xr[r];

  // Prefetch DPP-level twiddles from LDS (land during in-lane levels).
  float wA[16], wB[16];
  loadw_A<5>(wA, lds_bw, lane);
  loadw_A<4>(wB, lds_bw, lane);

  // Layout A: levels 9..6 in-lane, 5 and 4 via DPP.
  level_inlane<9, true>(v, xr, bw, lw);
  level_inlane<8, true>(v, xr, bw, lw);
  level_inlane<7, true>(v, xr, bw, lw);
  level_inlane<6, true>(v, xr, bw, lw);
  level_dpp<5, true>(v, xr, wA, lw, lane);
  level_dpp<4, true>(v, xr, wB, lw, lane);

  // Transpose v: A -> B (per-wave buffer, in-order DS, no barrier needed).
#pragma unroll
  for (int k = 0; k < 4; ++k) {
    float4 f;
    f.x = v[4*k+0]; f.y = v[4*k+1]; f.z = v[4*k+2]; f.w = v[4*k+3];
    *reinterpret_cast<float4*>(bufv + swz(lane*16 + 4*k)) = f;
  }

  // B-twiddles for the first two B-levels ride the same DS queue.
  float w3[2], w2[4], w1[8], w0[16];
  loadw_B<3>(w3, lds_bw, lane);
  loadw_B<2>(w2, lds_bw, lane);

  // Read back BOTH v and xr in B layout from LDS (no second global read).
#pragma unroll
  for (int r = 0; r < 16; ++r) v[r]  = bufv[swz(r*64 + lane)];
#pragma unroll
  for (int r = 0; r < 16; ++r) xr[r] = bufx[swz(r*64 + lane)];

  // Layout B: levels 3..0 all in-lane (pure VALU).
  level_B<3, true >(v, xr, w3, lw);
  loadw_B<1>(w1, lds_bw, lane);
  level_B<2, true >(v, xr, w2, lw);
  loadw_B<0>(w0, lds_bw, lane);
  level_B<1, false>(v, xr, w1, lw);   // RES[1] = False
  level_B<0, true >(v, xr, w0, lw);

  // Nontemporal coalesced stores: out is never re-read by the kernel — stream
  // past L2/L3 so write-allocation stops evicting x from Infinity Cache.
#pragma unroll
  for (int r = 0; r < 16; ++r)
    __builtin_nontemporal_store(v[r], &out[base + r*64 + lane]);
}

extern "C" void kernel_launch(void* const* d_in, const int* in_sizes, int n_in,
                              void* d_out, int out_size, void* d_ws, size_t ws_size,
                              hipStream_t stream) {
  const float* x  = (const float*)d_in[0];
  const float* bw = (const float*)d_in[1];
  const float* lw = (const float*)d_in[2];
  float* out = (float*)d_out;
  const int nvec = in_sizes[0] / VECLEN;        // 16384 vectors
  const int wpb = 4;                            // waves per block (256 threads)
  const int blocks = (nvec + wpb - 1) / wpb;    // 4096, exact
  rnnfft_kernel<<<blocks, 256, 0, stream>>>(x, bw, lw, out, nvec);
}